// Round 19
// baseline (886.142 us; speedup 1.0000x reference)
//
#include <hip/hip_runtime.h>
#include <cstddef>
#include <cstdint>

#define DIM 768
#define DINNER 1536
#define DSTATE 16
#define NLAYERS 4
#define SEQ 1024
#define XPROJ_N 1568
#define VOCAB 50257
#define NCHUNK 128
#define CHL 8  // SEQ / NCHUNK

typedef float f32x4 __attribute__((ext_vector_type(4)));
typedef __bf16 bf16x8 __attribute__((ext_vector_type(8)));
typedef __bf16 bf16x4 __attribute__((ext_vector_type(4)));

typedef __attribute__((address_space(1))) const unsigned int as1_u32;
typedef __attribute__((address_space(3))) unsigned int as3_u32;

__device__ __forceinline__ void gl_lds16(const void* g, void* l) {
  __builtin_amdgcn_global_load_lds((as1_u32*)g, (as3_u32*)l, 16, 0, 0);
}

__device__ __forceinline__ float siluf_(float x) {
  return x / (1.f + __expf(-x));
}
__device__ __forceinline__ float softplusf_(float x) {
  return (x > 20.f) ? x : log1pf(expf(x));
}

// ---------------- fused 4-array fp32 -> bf16 convert ----------------
struct Cvt4Args {
  const float* s[4];
  __bf16* d[4];
  int off[5];  // segment element offsets (contiguous, no padding)
};
__global__ __launch_bounds__(256) void k_cvt4(Cvt4Args a) {
  int e = (blockIdx.x * 256 + threadIdx.x) << 2;
  if (e >= a.off[4]) return;
  int seg = (e >= a.off[1]) + (e >= a.off[2]) + (e >= a.off[3]);
  int le = e - a.off[seg];
  f32x4 v = *(const f32x4*)(a.s[seg] + le);
  bf16x4 h;
  h.x = (__bf16)v.x; h.y = (__bf16)v.y; h.z = (__bf16)v.z; h.w = (__bf16)v.w;
  *(bf16x4*)(a.d[seg] + le) = h;
}

// ---------------- embedding gather ----------------
__global__ __launch_bounds__(256) void k_embed(const int* __restrict__ tok,
                                               const float* __restrict__ emb,
                                               float* __restrict__ X) {
  int i4 = blockIdx.x * 256 + threadIdx.x;  // over 1024*192 float4s
  int s = i4 / 192;
  int d4 = i4 - s * 192;
  const f32x4* src = (const f32x4*)(emb + (size_t)tok[s] * DIM);
  ((f32x4*)X)[i4] = src[d4];
}

// ---------------- rmsnorm (fp32 in, bf16 out) ----------------
__global__ __launch_bounds__(256) void k_rmsnorm(const float* __restrict__ x,
                                                 const float* __restrict__ w,
                                                 __bf16* __restrict__ o) {
  int s = blockIdx.x;
  const float* xr = x + (size_t)s * DIM;
  __bf16* orow = o + (size_t)s * DIM;
  int t = threadIdx.x;
  float v0 = xr[t], v1 = xr[t + 256], v2 = xr[t + 512];
  float acc = v0 * v0 + v1 * v1 + v2 * v2;
#pragma unroll
  for (int m = 32; m >= 1; m >>= 1) acc += __shfl_down(acc, m, 64);
  __shared__ float sred[4];
  if ((t & 63) == 0) sred[t >> 6] = acc;
  __syncthreads();
  float tot = sred[0] + sred[1] + sred[2] + sred[3];
  float rs = rsqrtf(tot * (1.f / 768.f) + 1e-6f);
  orow[t] = (__bf16)(v0 * rs * w[t]);
  orow[t + 256] = (__bf16)(v1 * rs * w[t + 256]);
  orow[t + 512] = (__bf16)(v2 * rs * w[t + 512]);
}

// -------- layer GEMM (bf16 both operands, quad-buffer pair-step loop) ----------
// 64x64 tile, both operands via global_load_lds; ONE barrier per 64 K.
// XCD-aware bijective block swizzle (grid x*y % 8 == 0 for all call sites).
// EPI: 0 = bf16 store, 2 = fp32 residual atomic +=, 3 = fp32 store (+zstride),
//      4 = bf16 store + fp32 aux copy of cols >= DINNER
template <int EPI>
__global__ __launch_bounds__(256)
void k_gemm2(const __bf16* __restrict__ A, int lda,
             const __bf16* __restrict__ Wb, int ldb,
             int N, int K,
             float* __restrict__ aux,
             void* __restrict__ Cv, int ldc,
             int zstride) {
  __shared__ __align__(16) __bf16 As[4][64 * 32];
  __shared__ __align__(16) __bf16 Bs[4][64 * 32];
  const int tid = threadIdx.x;
  // XCD swizzle (M fastest after decode)
  const int gx = gridDim.x;
  int id = blockIdx.y * gx + blockIdx.x;
  const int cpx = (gx * gridDim.y) >> 3;
  id = (id & 7) * cpx + (id >> 3);
  const int bm = (id % gx) * 64;
  const int bn = (id / gx) * 64;
  const int koff = blockIdx.z * K;
  const int lane = tid & 63;
  const int wv = tid >> 6;
  const int wm = (wv >> 1) * 32;
  const int wn = (wv & 1) * 32;
  const int lr = lane & 15;
  const int kb = lane >> 4;
  const int rdoff = ((kb ^ ((lr >> 1) & 3)) << 3);  // de-swizzle for ds_read

  f32x4 acc[2][2];
#pragma unroll
  for (int i = 0; i < 2; ++i)
#pragma unroll
    for (int j = 0; j < 2; ++j) acc[i][j] = (f32x4){0.f, 0.f, 0.f, 0.f};

  const int srow = wv * 16 + (lane >> 2);
  const int scs = (((lane & 3) ^ ((lane >> 3) & 3)) << 3);
  const __bf16* Ap = A + (size_t)(bm + srow) * lda + koff + scs;
  int rn0 = bn + srow;
  if (rn0 > N - 1) rn0 = N - 1;  // clamped rows only feed cols >= N
  const __bf16* Bp = Wb + (size_t)rn0 * ldb + koff + scs;

  auto stageA = [&](int b, int kt) {
    gl_lds16(Ap + (kt << 5), &As[b][wv * 512]);
  };
  auto stageB = [&](int b, int kt) {
    gl_lds16(Bp + (kt << 5), &Bs[b][wv * 512]);
  };

  stageA(0, 0); stageB(0, 0);
  stageA(1, 1); stageB(1, 1);
  __syncthreads();

  const int nK = K >> 5;  // even (K % 64 == 0)
  int cur = 0;
  for (int kt = 0; kt < nK; kt += 2) {
    const bool more = (kt + 2 < nK);
    if (more) {
      stageA(cur ^ 2, kt + 2); stageB(cur ^ 2, kt + 2);
      stageA((cur ^ 2) | 1, kt + 3); stageB((cur ^ 2) | 1, kt + 3);
    }
#pragma unroll
    for (int s = 0; s < 2; ++s) {
      const int b = cur + s;
      bf16x8 af[2], bfr[2];
#pragma unroll
      for (int i = 0; i < 2; ++i)
        af[i] = *(const bf16x8*)(&As[b][(wm + i * 16 + lr) * 32 + rdoff]);
#pragma unroll
      for (int j = 0; j < 2; ++j)
        bfr[j] = *(const bf16x8*)(&Bs[b][(wn + j * 16 + lr) * 32 + rdoff]);
#pragma unroll
      for (int i = 0; i < 2; ++i)
#pragma unroll
        for (int j = 0; j < 2; ++j)
          acc[i][j] = __builtin_amdgcn_mfma_f32_16x16x32_bf16(bfr[j], af[i], acc[i][j], 0, 0, 0);
    }
    __syncthreads();
    cur ^= 2;
  }

#pragma unroll
  for (int i = 0; i < 2; ++i) {
    const int row = bm + wm + i * 16 + lr;
#pragma unroll
    for (int j = 0; j < 2; ++j) {
      const int col = bn + wn + j * 16 + (kb << 2);
      f32x4 v = acc[i][j];
      if (EPI == 0) {
        if (col < N) {
          bf16x4 h;
          h.x = (__bf16)v.x; h.y = (__bf16)v.y; h.z = (__bf16)v.z; h.w = (__bf16)v.w;
          *(bf16x4*)((__bf16*)Cv + (size_t)row * ldc + col) = h;
        }
      } else if (EPI == 2) {
        if (col < N) {
          float* cp = (float*)Cv + (size_t)row * ldc + col;
          unsafeAtomicAdd(cp + 0, v.x);
          unsafeAtomicAdd(cp + 1, v.y);
          unsafeAtomicAdd(cp + 2, v.z);
          unsafeAtomicAdd(cp + 3, v.w);
        }
      } else if (EPI == 3) {
        float* cp = (float*)Cv + (size_t)blockIdx.z * zstride +
                    (size_t)row * ldc + col;
        if (col + 3 < N) {
          *(f32x4*)cp = v;
        } else {
#pragma unroll
          for (int r = 0; r < 4; ++r)
            if (col + r < N) cp[r] = v[r];
        }
      } else {  // EPI == 4
        if (col < N) {
          bf16x4 h;
          h.x = (__bf16)v.x; h.y = (__bf16)v.y; h.z = (__bf16)v.z; h.w = (__bf16)v.w;
          *(bf16x4*)((__bf16*)Cv + (size_t)row * ldc + col) = h;
          if (col >= DINNER)
            *(f32x4*)(aux + (size_t)row * 32 + (col - DINNER)) = v;
        }
      }
    }
  }
}

// ---------------- general GEMM (fp32-W reg-staged, DEPTH-2 B prefetch) ---------
// lm_head: TM=128,TN=128,SWZ=1. B loads issued 2 K-steps ahead so the
// ds_write consumes registers loaded a full iteration earlier (no vmem stall
// between MFMA and barrier). LDS/tiling/barriers identical to the proven r18.
template <int EPI, int SWZ, int TM, int TN>
__global__ __launch_bounds__(256)
void k_gemm(const __bf16* __restrict__ A, int lda,
            const float* __restrict__ Wf, int ldb,
            int N, int K,
            float* __restrict__ aux,
            void* __restrict__ Cv, int ldc,
            int zstride) {
  constexpr int MI = TM / 32;
  constexpr int NJ = TN / 32;
  constexpr int APASS = TM / 64;
  constexpr int BPASS = TN / 32;
  __shared__ __align__(16) __bf16 As[2][TM * 32];
  __shared__ __align__(16) __bf16 Bs[2][TN * 32];
  const int tid = threadIdx.x;
  int bx = blockIdx.x, by = blockIdx.y;
  if (SWZ) {
    const int gx = gridDim.x;
    const int id = by * gx + bx;
    const int cpx = (gx * gridDim.y) >> 3;
    const int id2 = (id & 7) * cpx + (id >> 3);
    bx = id2 % gx;  // M fastest
    by = id2 / gx;
  }
  const int bm = bx * TM;
  const int bn = by * TN;
  const int koff = blockIdx.z * K;
  const int lane = tid & 63;
  const int wv = tid >> 6;
  const int wm = (wv >> 1) * (MI * 16);
  const int wn = (wv & 1) * (TN / 2);
  const int lr = lane & 15;
  const int kb = lane >> 4;
  const int rdoff = ((kb ^ ((lr >> 1) & 3)) << 3);

  f32x4 acc[MI][NJ];
#pragma unroll
  for (int i = 0; i < MI; ++i)
#pragma unroll
    for (int j = 0; j < NJ; ++j) acc[i][j] = (f32x4){0.f, 0.f, 0.f, 0.f};

  const int srow = wv * 16 + (lane >> 2);
  const int scs = (((lane & 3) ^ ((lane >> 3) & 3)) << 3);
  const __bf16* Ap = A + (size_t)(bm + srow) * lda + koff + scs;
  const size_t a64 = (size_t)64 * lda;

  const int r0 = tid >> 3;
  const int c4 = (tid & 7) << 2;
  const int bwr = (((c4 >> 3) ^ ((r0 >> 1) & 3)) << 3) | (c4 & 7);
  const float* Wp = Wf + koff + c4;

  auto stageA = [&](int b, int kt) {
    const int k0 = kt << 5;
#pragma unroll
    for (int ap = 0; ap < APASS; ++ap)
      gl_lds16(Ap + k0 + ap * a64, &As[b][wv * 512 + ap * 2048]);
  };
  f32x4 breg[2][BPASS];  // breg[t & 1] holds tile t
  auto loadB = [&](int kt, int s) {
#pragma unroll
    for (int p = 0; p < BPASS; ++p) {
      int rn = bn + r0 + (p << 5);
      if (rn > N - 1) rn = N - 1;
      breg[s][p] = *(const f32x4*)(Wp + (size_t)rn * ldb + (kt << 5));
    }
  };
  auto writeB = [&](int b, int s) {
#pragma unroll
    for (int p = 0; p < BPASS; ++p) {
      bf16x4 bh;
      bh.x = (__bf16)breg[s][p].x; bh.y = (__bf16)breg[s][p].y;
      bh.z = (__bf16)breg[s][p].z; bh.w = (__bf16)breg[s][p].w;
      *(bf16x4*)(&Bs[b][(r0 + (p << 5)) * 32 + bwr]) = bh;
    }
  };

  const int nK = K >> 5;
  // prologue: tile 0 staged+written; tile 1 loaded to regs (stays in flight)
  stageA(0, 0);
  loadB(0, 0);
  writeB(0, 0);
  if (nK > 1) loadB(1, 1);
  __syncthreads();

  int cur = 0;
  for (int kt = 0; kt < nK; ++kt) {
    const bool more1 = (kt + 1 < nK);
    const bool more2 = (kt + 2 < nK);
    if (more1) stageA(cur ^ 1, kt + 1);
    if (more2) loadB(kt + 2, kt & 1);  // overwrites tile kt's regs (written last iter)
    bf16x8 af[MI], bfr[NJ];
#pragma unroll
    for (int i = 0; i < MI; ++i)
      af[i] = *(const bf16x8*)(&As[cur][(wm + i * 16 + lr) * 32 + rdoff]);
#pragma unroll
    for (int j = 0; j < NJ; ++j)
      bfr[j] = *(const bf16x8*)(&Bs[cur][(wn + j * 16 + lr) * 32 + rdoff]);
#pragma unroll
    for (int i = 0; i < MI; ++i)
#pragma unroll
      for (int j = 0; j < NJ; ++j)
        acc[i][j] = __builtin_amdgcn_mfma_f32_16x16x32_bf16(bfr[j], af[i], acc[i][j], 0, 0, 0);
    if (more1) writeB(cur ^ 1, (kt + 1) & 1);  // regs loaded a full iter ago
    __syncthreads();
    cur ^= 1;
  }

#pragma unroll
  for (int i = 0; i < MI; ++i) {
    const int row = bm + wm + i * 16 + lr;
#pragma unroll
    for (int j = 0; j < NJ; ++j) {
      const int col = bn + wn + j * 16 + (kb << 2);
      f32x4 v = acc[i][j];
      if (EPI == 0) {
        if (col < N) {
          bf16x4 h;
          h.x = (__bf16)v.x; h.y = (__bf16)v.y; h.z = (__bf16)v.z; h.w = (__bf16)v.w;
          *(bf16x4*)((__bf16*)Cv + (size_t)row * ldc + col) = h;
        }
      } else if (EPI == 2) {
        if (col < N) {
          float* cp = (float*)Cv + (size_t)row * ldc + col;
          unsafeAtomicAdd(cp + 0, v.x);
          unsafeAtomicAdd(cp + 1, v.y);
          unsafeAtomicAdd(cp + 2, v.z);
          unsafeAtomicAdd(cp + 3, v.w);
        }
      } else if (EPI == 3) {
        float* cp = (float*)Cv + (size_t)blockIdx.z * zstride +
                    (size_t)row * ldc + col;
        if (col + 3 < N) {
          *(f32x4*)cp = v;
        } else {
#pragma unroll
          for (int r = 0; r < 4; ++r)
            if (col + r < N) cp[r] = v[r];
        }
      } else {  // EPI == 4
        if (col < N) {
          bf16x4 h;
          h.x = (__bf16)v.x; h.y = (__bf16)v.y; h.z = (__bf16)v.z; h.w = (__bf16)v.w;
          *(bf16x4*)((__bf16*)Cv + (size_t)row * ldc + col) = h;
          if (col >= DINNER)
            *(f32x4*)(aux + (size_t)row * 32 + (col - DINNER)) = v;
        }
      }
    }
  }
}

// ------- causal depthwise conv (width 4) + bias + silu, 4 ch/thread ------------
__global__ __launch_bounds__(384) void k_conv_silu(const __bf16* __restrict__ XZ,
                                                   const float* __restrict__ cw,
                                                   const float* __restrict__ cb,
                                                   __bf16* __restrict__ out) {
  const int s = blockIdx.x;
  const int d = threadIdx.x << 2;  // 384 threads x 4 ch = 1536
  f32x4 w0 = *(const f32x4*)(cw + (d + 0) * 4);
  f32x4 w1 = *(const f32x4*)(cw + (d + 1) * 4);
  f32x4 w2 = *(const f32x4*)(cw + (d + 2) * 4);
  f32x4 w3 = *(const f32x4*)(cw + (d + 3) * 4);
  f32x4 acc = *(const f32x4*)(cb + d);
#pragma unroll
  for (int k = 0; k < 4; ++k) {
    const int ss = s - 3 + k;
    if (ss >= 0) {
      bf16x4 x = *(const bf16x4*)(XZ + (size_t)ss * (2 * DINNER) + d);
      acc.x += (float)x.x * w0[k];
      acc.y += (float)x.y * w1[k];
      acc.z += (float)x.z * w2[k];
      acc.w += (float)x.w * w3[k];
    }
  }
  bf16x4 o;
  o.x = (__bf16)siluf_(acc.x);
  o.y = (__bf16)siluf_(acc.y);
  o.z = (__bf16)siluf_(acc.z);
  o.w = (__bf16)siluf_(acc.w);
  *(bf16x4*)(out + (size_t)s * DINNER + d) = o;
}

// ---------------- chunked selective scan ----------------
// dt = softplus(DT[idx] + DT[idx + SEQ*DINNER] + dt_b[d])  (split-K partials)
__global__ __launch_bounds__(256) void k_scan1(const float* __restrict__ DT,
                                               const float* __restrict__ dt_b,
                                               const __bf16* __restrict__ XCS,
                                               const float* __restrict__ BC,
                                               const float* __restrict__ A_log,
                                               float* __restrict__ Hloc,
                                               float* __restrict__ Ssum) {
  const int d = blockIdx.x * 256 + threadIdx.x;
  const int c = blockIdx.y;
  const int t0 = c * CHL;
  __shared__ float s_b[CHL][16];
  if (threadIdx.x < CHL * 16) {
    int li = threadIdx.x;
    s_b[li >> 4][li & 15] = BC[(size_t)(t0 + (li >> 4)) * 32 + (li & 15)];
  }
  float a[16];
  const f32x4* alp = (const f32x4*)(A_log + (size_t)d * 16);
#pragma unroll
  for (int q = 0; q < 4; ++q) {
    f32x4 v = alp[q];
    a[q * 4 + 0] = -expf(v.x); a[q * 4 + 1] = -expf(v.y);
    a[q * 4 + 2] = -expf(v.z); a[q * 4 + 3] = -expf(v.w);
  }
  const float bias = dt_b[d];
  float h[16];
#pragma unroll
  for (int n = 0; n < 16; ++n) h[n] = 0.f;
  float ss = 0.f;
  __syncthreads();
#pragma unroll
  for (int tt = 0; tt < CHL; ++tt) {
    const size_t idx = (size_t)(t0 + tt) * DINNER + d;
    const float dtv = softplusf_(DT[idx] + DT[idx + (size_t)SEQ * DINNER] + bias);
    const float xv = (float)XCS[idx];
    const float u = dtv * xv;
    ss += dtv;
#pragma unroll
    for (int n = 0; n < 16; ++n)
      h[n] = h[n] * __expf(dtv * a[n]) + u * s_b[tt][n];
  }
  float* hp = Hloc + ((size_t)c * DINNER + d) * 16;
#pragma unroll
  for (int q = 0; q < 4; ++q)
    ((f32x4*)hp)[q] = (f32x4){h[q * 4], h[q * 4 + 1], h[q * 4 + 2], h[q * 4 + 3]};
  Ssum[(size_t)c * DINNER + d] = ss;
}

// K2: in-place rescan over chunks: H[c] becomes chunk-ENTRY state
__global__ __launch_bounds__(256) void k_scan2(float* __restrict__ H,
                                               const float* __restrict__ Ssum,
                                               const float* __restrict__ A_log) {
  const int idx = blockIdx.x * 256 + threadIdx.x;  // over DINNER*16
  const int d = idx >> 4;
  const float a = -expf(A_log[idx]);
  float h = 0.f;
#pragma unroll 8
  for (int c = 0; c < NCHUNK; ++c) {
    float* p = H + (size_t)c * (DINNER * DSTATE) + idx;
    const float bl = *p;
    const float sv = Ssum[(size_t)c * DINNER + d];
    *p = h;
    h = h * __expf(a * sv) + bl;
  }
}

// K3: replay each chunk from entry state, y = h.C + D*x, fused silu(z) gate
__global__ __launch_bounds__(256) void k_scan3(const float* __restrict__ DT,
                                               const float* __restrict__ dt_b,
                                               const __bf16* __restrict__ XCS,
                                               const __bf16* __restrict__ XZ,
                                               const float* __restrict__ BC,
                                               const float* __restrict__ A_log,
                                               const float* __restrict__ Dp,
                                               const float* __restrict__ H,
                                               __bf16* __restrict__ Y) {
  const int d = blockIdx.x * 256 + threadIdx.x;
  const int c = blockIdx.y;
  const int t0 = c * CHL;
  __shared__ float s_bc[CHL][32];
  {
    int li = threadIdx.x;  // CHL*32 = 256
    s_bc[li >> 5][li & 31] = BC[(size_t)(t0 + (li >> 5)) * 32 + (li & 31)];
  }
  float a[16], h[16];
  const f32x4* alp = (const f32x4*)(A_log + (size_t)d * 16);
  const f32x4* hp = (const f32x4*)(H + ((size_t)c * DINNER + d) * 16);
#pragma unroll
  for (int q = 0; q < 4; ++q) {
    f32x4 v = alp[q];
    a[q * 4 + 0] = -expf(v.x); a[q * 4 + 1] = -expf(v.y);
    a[q * 4 + 2] = -expf(v.z); a[q * 4 + 3] = -expf(v.w);
    f32x4 hv = hp[q];
    h[q * 4 + 0] = hv.x; h[q * 4 + 1] = hv.y;
    h[q * 4 + 2] = hv.z; h[q * 4 + 3] = hv.w;
  }
  const float Dd = Dp[d];
  const float bias = dt_b[d];
  __syncthreads();
#pragma unroll
  for (int tt = 0; tt < CHL; ++tt) {
    const size_t idx = (size_t)(t0 + tt) * DINNER + d;
    const float dtv = softplusf_(DT[idx] + DT[idx + (size_t)SEQ * DINNER] + bias);
    const float xv = (float)XCS[idx];
    const float zv = (float)XZ[(size_t)(t0 + tt) * (2 * DINNER) + DINNER + d];
    const float u = dtv * xv;
    float y = 0.f;
#pragma unroll
    for (int n = 0; n < 16; ++n) {
      h[n] = h[n] * __expf(dtv * a[n]) + u * s_bc[tt][n];
      y += h[n] * s_bc[tt][16 + n];
    }
    Y[idx] = (__bf16)((y + Dd * xv) * siluf_(zv));
  }
}

extern "C" void kernel_launch(void* const* d_in, const int* in_sizes, int n_in,
                              void* d_out, int out_size, void* d_ws, size_t ws_size,
                              hipStream_t stream) {
  const int* tokens = (const int*)d_in[0];
  const float* embedding = (const float*)d_in[1];
  const float* norm_w = (const float*)d_in[2];
  const float* in_proj_w = (const float*)d_in[3];
  const float* conv_w = (const float*)d_in[4];
  const float* conv_b = (const float*)d_in[5];
  const float* x_proj_w = (const float*)d_in[6];
  const float* dt_w = (const float*)d_in[7];
  const float* dt_b = (const float*)d_in[8];
  const float* A_log = (const float*)d_in[9];
  const float* Dp = (const float*)d_in[10];
  const float* out_proj_w = (const float*)d_in[11];
  const float* normf_w = (const float*)d_in[12];
  const float* lm_head_w = (const float*)d_in[13];
  float* logits = (float*)d_out;

  char* ws = (char*)d_ws;
  float* X = (float*)(ws + 0);                   // 1024*768 f32
  __bf16* XN = (__bf16*)(ws + 3145728);          // 1024*768 bf16
  __bf16* XZ = (__bf16*)(ws + 4718592);          // 1024*3072 bf16
  __bf16* XCS = (__bf16*)(ws + 11010048);        // 1024*1536 bf16
  __bf16* XP = (__bf16*)(ws + 14155776);         // 1024*1568 bf16
  float* DT = (float*)(ws + 17367040);           // 2 x 1024*1536 f32 (split-K)
  float* BC = (float*)(ws + 29949952);           // 1024*32 f32
  __bf16* Y = (__bf16*)(ws + 30081024);          // 1024*1536 bf16
  float* Hloc = (float*)(ws + 33226752);         // 128*1536*16 f32 (12.6MB)
  float* Ssum = (float*)(ws + 45809664);         // 128*1536 f32
  __bf16* Wip = (__bf16*)(ws + 46596096);        // 4*3072*768  (18.87MB)
  __bf16* Wxp = (__bf16*)(ws + 65470464);        // 4*1568*1536 (19.27MB)
  __bf16* Wdt = (__bf16*)(ws + 84738048);        // 4*1536*1536 (18.87MB)
  __bf16* Wop = (__bf16*)(ws + 103612416);       // 4*768*1536  (9.44MB)
  const bool full = ws_size >= 113049600ull;     // proven >= 134479872 (r3)

  k_embed<<<768, 256, 0, stream>>>(tokens, embedding, X);
  if (full) {
    Cvt4Args ca;
    ca.s[0] = in_proj_w;  ca.d[0] = Wip;
    ca.s[1] = x_proj_w;   ca.d[1] = Wxp;
    ca.s[2] = dt_w;       ca.d[2] = Wdt;
    ca.s[3] = out_proj_w; ca.d[3] = Wop;
    ca.off[0] = 0;
    ca.off[1] = NLAYERS * 3072 * DIM;                   // 9437184
    ca.off[2] = ca.off[1] + NLAYERS * XPROJ_N * DINNER; // +9633792
    ca.off[3] = ca.off[2] + NLAYERS * DINNER * DINNER;  // +9437184
    ca.off[4] = ca.off[3] + NLAYERS * DIM * DINNER;     // = 33226752
    k_cvt4<<<(33226752 / 4 + 255) / 256, 256, 0, stream>>>(ca);
  }

  for (int l = 0; l < NLAYERS; ++l) {
    const float* Al = A_log + (size_t)l * DINNER * DSTATE;
    const float* bl = dt_b + (size_t)l * DINNER;

    k_rmsnorm<<<SEQ, 256, 0, stream>>>(X, norm_w + (size_t)l * DIM, XN);
    if (full) {
      k_gemm2<0><<<dim3(16, 48), 256, 0, stream>>>(
          XN, DIM, Wip + (size_t)l * 3072 * DIM, DIM, 2 * DINNER, DIM,
          nullptr, XZ, 2 * DINNER, 0);
    } else {
      k_gemm<0, 0, 64, 64><<<dim3(16, 48), 256, 0, stream>>>(
          XN, DIM, in_proj_w + (size_t)l * 3072 * DIM, DIM, 2 * DINNER,
          DIM, nullptr, XZ, 2 * DINNER, 0);
    }
    k_conv_silu<<<SEQ, 384, 0, stream>>>(
        XZ, conv_w + (size_t)l * DINNER * 4, conv_b + (size_t)l * DINNER, XCS);
    if (full) {
      k_gemm2<4><<<dim3(16, 25), 256, 0, stream>>>(
          XCS, DINNER, Wxp + (size_t)l * XPROJ_N * DINNER, DINNER,
          XPROJ_N, DINNER, BC, XP, XPROJ_N, 0);
      k_gemm2<3><<<dim3(16, 24, 2), 256, 0, stream>>>(
          XP, XPROJ_N, Wdt + (size_t)l * DINNER * DINNER, DINNER, DINNER,
          DINNER / 2, nullptr, DT, DINNER, SEQ * DINNER);
    } else {
      k_gemm<4, 0, 64, 64><<<dim3(16, 25), 256, 0, stream>>>(
          XCS, DINNER, x_proj_w + (size_t)l * XPROJ_N * DINNER, DINNER,
          XPROJ_N, DINNER, BC, XP, XPROJ_N, 0);
      k_gemm<3, 0, 64, 64><<<dim3(16, 24, 2), 256, 0, stream>>>(
          XP, XPROJ_N, dt_w + (size_t)l * DINNER * DINNER, DINNER,
          DINNER, DINNER / 2, nullptr, DT, DINNER, SEQ * DINNER);
    }
    k_scan1<<<dim3(6, NCHUNK), 256, 0, stream>>>(DT, bl, XCS, BC, Al, Hloc, Ssum);
    k_scan2<<<96, 256, 0, stream>>>(Hloc, Ssum, Al);
    k_scan3<<<dim3(6, NCHUNK), 256, 0, stream>>>(DT, bl, XCS, XZ, BC, Al,
                                                 Dp + (size_t)l * DINNER, Hloc, Y);
    if (full) {
      k_gemm2<2><<<dim3(16, 12, 2), 256, 0, stream>>>(
          Y, DINNER, Wop + (size_t)l * DIM * DINNER, DINNER, DIM,
          DINNER / 2, nullptr, X, DIM, 0);
    } else {
      k_gemm<2, 0, 64, 64><<<dim3(16, 12, 2), 256, 0, stream>>>(
          Y, DINNER, out_proj_w + (size_t)l * DIM * DINNER, DINNER,
          DIM, DINNER / 2, nullptr, X, DIM, 0);
    }
  }
  k_rmsnorm<<<SEQ, 256, 0, stream>>>(X, normf_w, XN);
  // lm_head: 128x128 dbuf + depth-2 B prefetch + XCD swizzle
  k_gemm<3, 1, 128, 128><<<dim3(8, 393), 256, 0, stream>>>(
      XN, DIM, lm_head_w, DIM, VOCAB, DIM, nullptr, logits, VOCAB, 0);
}

// Round 20
// 728.499 us; speedup vs baseline: 1.2164x; 1.2164x over previous
//
#include <hip/hip_runtime.h>
#include <cstddef>
#include <cstdint>

#define DIM 768
#define DINNER 1536
#define DSTATE 16
#define NLAYERS 4
#define SEQ 1024
#define XPROJ_N 1568
#define VOCAB 50257
#define NCHUNK 128
#define CHL 8  // SEQ / NCHUNK

typedef float f32x4 __attribute__((ext_vector_type(4)));
typedef __bf16 bf16x8 __attribute__((ext_vector_type(8)));
typedef __bf16 bf16x4 __attribute__((ext_vector_type(4)));

typedef __attribute__((address_space(1))) const unsigned int as1_u32;
typedef __attribute__((address_space(3))) unsigned int as3_u32;

__device__ __forceinline__ void gl_lds16(const void* g, void* l) {
  __builtin_amdgcn_global_load_lds((as1_u32*)g, (as3_u32*)l, 16, 0, 0);
}

__device__ __forceinline__ float siluf_(float x) {
  return x / (1.f + __expf(-x));
}
__device__ __forceinline__ float softplusf_(float x) {
  return (x > 20.f) ? x : log1pf(expf(x));
}

// ---------------- fused 4-array fp32 -> bf16 convert ----------------
struct Cvt4Args {
  const float* s[4];
  __bf16* d[4];
  int off[5];  // segment element offsets (contiguous, no padding)
};
__global__ __launch_bounds__(256) void k_cvt4(Cvt4Args a) {
  int e = (blockIdx.x * 256 + threadIdx.x) << 2;
  if (e >= a.off[4]) return;
  int seg = (e >= a.off[1]) + (e >= a.off[2]) + (e >= a.off[3]);
  int le = e - a.off[seg];
  f32x4 v = *(const f32x4*)(a.s[seg] + le);
  bf16x4 h;
  h.x = (__bf16)v.x; h.y = (__bf16)v.y; h.z = (__bf16)v.z; h.w = (__bf16)v.w;
  *(bf16x4*)(a.d[seg] + le) = h;
}

// ---------------- embedding gather ----------------
__global__ __launch_bounds__(256) void k_embed(const int* __restrict__ tok,
                                               const float* __restrict__ emb,
                                               float* __restrict__ X) {
  int i4 = blockIdx.x * 256 + threadIdx.x;  // over 1024*192 float4s
  int s = i4 / 192;
  int d4 = i4 - s * 192;
  const f32x4* src = (const f32x4*)(emb + (size_t)tok[s] * DIM);
  ((f32x4*)X)[i4] = src[d4];
}

// ---------------- rmsnorm (fp32 in, bf16 out) ----------------
__global__ __launch_bounds__(256) void k_rmsnorm(const float* __restrict__ x,
                                                 const float* __restrict__ w,
                                                 __bf16* __restrict__ o) {
  int s = blockIdx.x;
  const float* xr = x + (size_t)s * DIM;
  __bf16* orow = o + (size_t)s * DIM;
  int t = threadIdx.x;
  float v0 = xr[t], v1 = xr[t + 256], v2 = xr[t + 512];
  float acc = v0 * v0 + v1 * v1 + v2 * v2;
#pragma unroll
  for (int m = 32; m >= 1; m >>= 1) acc += __shfl_down(acc, m, 64);
  __shared__ float sred[4];
  if ((t & 63) == 0) sred[t >> 6] = acc;
  __syncthreads();
  float tot = sred[0] + sred[1] + sred[2] + sred[3];
  float rs = rsqrtf(tot * (1.f / 768.f) + 1e-6f);
  orow[t] = (__bf16)(v0 * rs * w[t]);
  orow[t + 256] = (__bf16)(v1 * rs * w[t + 256]);
  orow[t + 512] = (__bf16)(v2 * rs * w[t + 512]);
}

// -------- layer GEMM (bf16 both operands, quad-buffer pair-step loop) ----------
// 64x64 tile, both operands via global_load_lds; ONE barrier per 64 K.
// XCD-aware bijective block swizzle (grid x*y % 8 == 0 for all call sites):
// each XCD gets a contiguous chunk of N-tile groups -> B panels L2-local.
// EPI: 0 = bf16 store, 2 = fp32 residual atomic +=, 3 = fp32 store (+zstride),
//      4 = bf16 store + fp32 aux copy of cols >= DINNER
template <int EPI>
__global__ __launch_bounds__(256)
void k_gemm2(const __bf16* __restrict__ A, int lda,
             const __bf16* __restrict__ Wb, int ldb,
             int N, int K,
             float* __restrict__ aux,
             void* __restrict__ Cv, int ldc,
             int zstride) {
  __shared__ __align__(16) __bf16 As[4][64 * 32];
  __shared__ __align__(16) __bf16 Bs[4][64 * 32];
  const int tid = threadIdx.x;
  // XCD swizzle (M fastest after decode)
  const int gx = gridDim.x;
  int id = blockIdx.y * gx + blockIdx.x;
  const int cpx = (gx * gridDim.y) >> 3;
  id = (id & 7) * cpx + (id >> 3);
  const int bm = (id % gx) * 64;
  const int bn = (id / gx) * 64;
  const int koff = blockIdx.z * K;
  const int lane = tid & 63;
  const int wv = tid >> 6;
  const int wm = (wv >> 1) * 32;
  const int wn = (wv & 1) * 32;
  const int lr = lane & 15;
  const int kb = lane >> 4;
  const int rdoff = ((kb ^ ((lr >> 1) & 3)) << 3);  // de-swizzle for ds_read

  f32x4 acc[2][2];
#pragma unroll
  for (int i = 0; i < 2; ++i)
#pragma unroll
    for (int j = 0; j < 2; ++j) acc[i][j] = (f32x4){0.f, 0.f, 0.f, 0.f};

  const int srow = wv * 16 + (lane >> 2);
  const int scs = (((lane & 3) ^ ((lane >> 3) & 3)) << 3);
  const __bf16* Ap = A + (size_t)(bm + srow) * lda + koff + scs;
  int rn0 = bn + srow;
  if (rn0 > N - 1) rn0 = N - 1;  // clamped rows only feed cols >= N
  const __bf16* Bp = Wb + (size_t)rn0 * ldb + koff + scs;

  auto stageA = [&](int b, int kt) {
    gl_lds16(Ap + (kt << 5), &As[b][wv * 512]);
  };
  auto stageB = [&](int b, int kt) {
    gl_lds16(Bp + (kt << 5), &Bs[b][wv * 512]);
  };

  stageA(0, 0); stageB(0, 0);
  stageA(1, 1); stageB(1, 1);
  __syncthreads();

  const int nK = K >> 5;  // even (K % 64 == 0)
  int cur = 0;
  for (int kt = 0; kt < nK; kt += 2) {
    const bool more = (kt + 2 < nK);
    if (more) {
      stageA(cur ^ 2, kt + 2); stageB(cur ^ 2, kt + 2);
      stageA((cur ^ 2) | 1, kt + 3); stageB((cur ^ 2) | 1, kt + 3);
    }
#pragma unroll
    for (int s = 0; s < 2; ++s) {
      const int b = cur + s;
      bf16x8 af[2], bfr[2];
#pragma unroll
      for (int i = 0; i < 2; ++i)
        af[i] = *(const bf16x8*)(&As[b][(wm + i * 16 + lr) * 32 + rdoff]);
#pragma unroll
      for (int j = 0; j < 2; ++j)
        bfr[j] = *(const bf16x8*)(&Bs[b][(wn + j * 16 + lr) * 32 + rdoff]);
#pragma unroll
      for (int i = 0; i < 2; ++i)
#pragma unroll
        for (int j = 0; j < 2; ++j)
          acc[i][j] = __builtin_amdgcn_mfma_f32_16x16x32_bf16(bfr[j], af[i], acc[i][j], 0, 0, 0);
    }
    __syncthreads();
    cur ^= 2;
  }

#pragma unroll
  for (int i = 0; i < 2; ++i) {
    const int row = bm + wm + i * 16 + lr;
#pragma unroll
    for (int j = 0; j < 2; ++j) {
      const int col = bn + wn + j * 16 + (kb << 2);
      f32x4 v = acc[i][j];
      if (EPI == 0) {
        if (col < N) {
          bf16x4 h;
          h.x = (__bf16)v.x; h.y = (__bf16)v.y; h.z = (__bf16)v.z; h.w = (__bf16)v.w;
          *(bf16x4*)((__bf16*)Cv + (size_t)row * ldc + col) = h;
        }
      } else if (EPI == 2) {
        if (col < N) {
          float* cp = (float*)Cv + (size_t)row * ldc + col;
          unsafeAtomicAdd(cp + 0, v.x);
          unsafeAtomicAdd(cp + 1, v.y);
          unsafeAtomicAdd(cp + 2, v.z);
          unsafeAtomicAdd(cp + 3, v.w);
        }
      } else if (EPI == 3) {
        float* cp = (float*)Cv + (size_t)blockIdx.z * zstride +
                    (size_t)row * ldc + col;
        if (col + 3 < N) {
          *(f32x4*)cp = v;
        } else {
#pragma unroll
          for (int r = 0; r < 4; ++r)
            if (col + r < N) cp[r] = v[r];
        }
      } else {  // EPI == 4
        if (col < N) {
          bf16x4 h;
          h.x = (__bf16)v.x; h.y = (__bf16)v.y; h.z = (__bf16)v.z; h.w = (__bf16)v.w;
          *(bf16x4*)((__bf16*)Cv + (size_t)row * ldc + col) = h;
          if (col >= DINNER)
            *(f32x4*)(aux + (size_t)row * 32 + (col - DINNER)) = v;
        }
      }
    }
  }
}

// ---------------- general GEMM (r7/r15 verified: fp32-W reg-staged) ------------
// Used for lm_head (TM=128,TN=128,SWZ=1 -> 183us proven) and as fallback.
template <int EPI, int SWZ, int TM, int TN>
__global__ __launch_bounds__(256)
void k_gemm(const __bf16* __restrict__ A, int lda,
            const float* __restrict__ Wf, int ldb,
            int N, int K,
            float* __restrict__ aux,
            void* __restrict__ Cv, int ldc,
            int zstride) {
  constexpr int MI = TM / 32;
  constexpr int NJ = TN / 32;
  constexpr int APASS = TM / 64;
  constexpr int BPASS = TN / 32;
  __shared__ __align__(16) __bf16 As[2][TM * 32];
  __shared__ __align__(16) __bf16 Bs[2][TN * 32];
  const int tid = threadIdx.x;
  int bx = blockIdx.x, by = blockIdx.y;
  if (SWZ) {
    const int gx = gridDim.x;
    const int id = by * gx + bx;
    const int cpx = (gx * gridDim.y) >> 3;
    const int id2 = (id & 7) * cpx + (id >> 3);
    bx = id2 % gx;  // M fastest
    by = id2 / gx;
  }
  const int bm = bx * TM;
  const int bn = by * TN;
  const int koff = blockIdx.z * K;
  const int lane = tid & 63;
  const int wv = tid >> 6;
  const int wm = (wv >> 1) * (MI * 16);
  const int wn = (wv & 1) * (TN / 2);
  const int lr = lane & 15;
  const int kb = lane >> 4;
  const int rdoff = ((kb ^ ((lr >> 1) & 3)) << 3);

  f32x4 acc[MI][NJ];
#pragma unroll
  for (int i = 0; i < MI; ++i)
#pragma unroll
    for (int j = 0; j < NJ; ++j) acc[i][j] = (f32x4){0.f, 0.f, 0.f, 0.f};

  const int srow = wv * 16 + (lane >> 2);
  const int scs = (((lane & 3) ^ ((lane >> 3) & 3)) << 3);
  const __bf16* Ap = A + (size_t)(bm + srow) * lda + koff + scs;
  const size_t a64 = (size_t)64 * lda;

  const int r0 = tid >> 3;
  const int c4 = (tid & 7) << 2;
  const int bwr = (((c4 >> 3) ^ ((r0 >> 1) & 3)) << 3) | (c4 & 7);
  const float* Wp = Wf + koff + c4;

  auto stageA = [&](int b, int kt) {
    const int k0 = kt << 5;
#pragma unroll
    for (int ap = 0; ap < APASS; ++ap)
      gl_lds16(Ap + k0 + ap * a64, &As[b][wv * 512 + ap * 2048]);
  };
  f32x4 breg[BPASS];
  auto loadB = [&](int kt) {
#pragma unroll
    for (int p = 0; p < BPASS; ++p) {
      int rn = bn + r0 + (p << 5);
      if (rn > N - 1) rn = N - 1;
      breg[p] = *(const f32x4*)(Wp + (size_t)rn * ldb + (kt << 5));
    }
  };
  auto writeB = [&](int b) {
#pragma unroll
    for (int p = 0; p < BPASS; ++p) {
      bf16x4 bh;
      bh.x = (__bf16)breg[p].x; bh.y = (__bf16)breg[p].y;
      bh.z = (__bf16)breg[p].z; bh.w = (__bf16)breg[p].w;
      *(bf16x4*)(&Bs[b][(r0 + (p << 5)) * 32 + bwr]) = bh;
    }
  };

  stageA(0, 0);
  loadB(0);
  writeB(0);
  __syncthreads();

  const int nK = K >> 5;
  int cur = 0;
  for (int kt = 0; kt < nK; ++kt) {
    const bool more = (kt + 1 < nK);
    if (more) {
      stageA(cur ^ 1, kt + 1);
      loadB(kt + 1);
    }
    bf16x8 af[MI], bfr[NJ];
#pragma unroll
    for (int i = 0; i < MI; ++i)
      af[i] = *(const bf16x8*)(&As[cur][(wm + i * 16 + lr) * 32 + rdoff]);
#pragma unroll
    for (int j = 0; j < NJ; ++j)
      bfr[j] = *(const bf16x8*)(&Bs[cur][(wn + j * 16 + lr) * 32 + rdoff]);
#pragma unroll
    for (int i = 0; i < MI; ++i)
#pragma unroll
      for (int j = 0; j < NJ; ++j)
        acc[i][j] = __builtin_amdgcn_mfma_f32_16x16x32_bf16(bfr[j], af[i], acc[i][j], 0, 0, 0);
    if (more) writeB(cur ^ 1);
    __syncthreads();
    cur ^= 1;
  }

#pragma unroll
  for (int i = 0; i < MI; ++i) {
    const int row = bm + wm + i * 16 + lr;
#pragma unroll
    for (int j = 0; j < NJ; ++j) {
      const int col = bn + wn + j * 16 + (kb << 2);
      f32x4 v = acc[i][j];
      if (EPI == 0) {
        if (col < N) {
          bf16x4 h;
          h.x = (__bf16)v.x; h.y = (__bf16)v.y; h.z = (__bf16)v.z; h.w = (__bf16)v.w;
          *(bf16x4*)((__bf16*)Cv + (size_t)row * ldc + col) = h;
        }
      } else if (EPI == 2) {
        if (col < N) {
          float* cp = (float*)Cv + (size_t)row * ldc + col;
          unsafeAtomicAdd(cp + 0, v.x);
          unsafeAtomicAdd(cp + 1, v.y);
          unsafeAtomicAdd(cp + 2, v.z);
          unsafeAtomicAdd(cp + 3, v.w);
        }
      } else if (EPI == 3) {
        float* cp = (float*)Cv + (size_t)blockIdx.z * zstride +
                    (size_t)row * ldc + col;
        if (col + 3 < N) {
          *(f32x4*)cp = v;
        } else {
#pragma unroll
          for (int r = 0; r < 4; ++r)
            if (col + r < N) cp[r] = v[r];
        }
      } else {  // EPI == 4
        if (col < N) {
          bf16x4 h;
          h.x = (__bf16)v.x; h.y = (__bf16)v.y; h.z = (__bf16)v.z; h.w = (__bf16)v.w;
          *(bf16x4*)((__bf16*)Cv + (size_t)row * ldc + col) = h;
          if (col >= DINNER)
            *(f32x4*)(aux + (size_t)row * 32 + (col - DINNER)) = v;
        }
      }
    }
  }
}

// ------- causal depthwise conv (width 4) + bias + silu, 4 ch/thread ------------
__global__ __launch_bounds__(384) void k_conv_silu(const __bf16* __restrict__ XZ,
                                                   const float* __restrict__ cw,
                                                   const float* __restrict__ cb,
                                                   __bf16* __restrict__ out) {
  const int s = blockIdx.x;
  const int d = threadIdx.x << 2;  // 384 threads x 4 ch = 1536
  f32x4 w0 = *(const f32x4*)(cw + (d + 0) * 4);
  f32x4 w1 = *(const f32x4*)(cw + (d + 1) * 4);
  f32x4 w2 = *(const f32x4*)(cw + (d + 2) * 4);
  f32x4 w3 = *(const f32x4*)(cw + (d + 3) * 4);
  f32x4 acc = *(const f32x4*)(cb + d);
#pragma unroll
  for (int k = 0; k < 4; ++k) {
    const int ss = s - 3 + k;
    if (ss >= 0) {
      bf16x4 x = *(const bf16x4*)(XZ + (size_t)ss * (2 * DINNER) + d);
      acc.x += (float)x.x * w0[k];
      acc.y += (float)x.y * w1[k];
      acc.z += (float)x.z * w2[k];
      acc.w += (float)x.w * w3[k];
    }
  }
  bf16x4 o;
  o.x = (__bf16)siluf_(acc.x);
  o.y = (__bf16)siluf_(acc.y);
  o.z = (__bf16)siluf_(acc.z);
  o.w = (__bf16)siluf_(acc.w);
  *(bf16x4*)(out + (size_t)s * DINNER + d) = o;
}

// ---------------- chunked selective scan ----------------
// dt = softplus(DT[idx] + DT[idx + SEQ*DINNER] + dt_b[d])  (split-K partials)
__global__ __launch_bounds__(256) void k_scan1(const float* __restrict__ DT,
                                               const float* __restrict__ dt_b,
                                               const __bf16* __restrict__ XCS,
                                               const float* __restrict__ BC,
                                               const float* __restrict__ A_log,
                                               float* __restrict__ Hloc,
                                               float* __restrict__ Ssum) {
  const int d = blockIdx.x * 256 + threadIdx.x;
  const int c = blockIdx.y;
  const int t0 = c * CHL;
  __shared__ float s_b[CHL][16];
  if (threadIdx.x < CHL * 16) {
    int li = threadIdx.x;
    s_b[li >> 4][li & 15] = BC[(size_t)(t0 + (li >> 4)) * 32 + (li & 15)];
  }
  float a[16];
  const f32x4* alp = (const f32x4*)(A_log + (size_t)d * 16);
#pragma unroll
  for (int q = 0; q < 4; ++q) {
    f32x4 v = alp[q];
    a[q * 4 + 0] = -expf(v.x); a[q * 4 + 1] = -expf(v.y);
    a[q * 4 + 2] = -expf(v.z); a[q * 4 + 3] = -expf(v.w);
  }
  const float bias = dt_b[d];
  float h[16];
#pragma unroll
  for (int n = 0; n < 16; ++n) h[n] = 0.f;
  float ss = 0.f;
  __syncthreads();
#pragma unroll
  for (int tt = 0; tt < CHL; ++tt) {
    const size_t idx = (size_t)(t0 + tt) * DINNER + d;
    const float dtv = softplusf_(DT[idx] + DT[idx + (size_t)SEQ * DINNER] + bias);
    const float xv = (float)XCS[idx];
    const float u = dtv * xv;
    ss += dtv;
#pragma unroll
    for (int n = 0; n < 16; ++n)
      h[n] = h[n] * __expf(dtv * a[n]) + u * s_b[tt][n];
  }
  float* hp = Hloc + ((size_t)c * DINNER + d) * 16;
#pragma unroll
  for (int q = 0; q < 4; ++q)
    ((f32x4*)hp)[q] = (f32x4){h[q * 4], h[q * 4 + 1], h[q * 4 + 2], h[q * 4 + 3]};
  Ssum[(size_t)c * DINNER + d] = ss;
}

// K2: in-place rescan over chunks: H[c] becomes chunk-ENTRY state
__global__ __launch_bounds__(256) void k_scan2(float* __restrict__ H,
                                               const float* __restrict__ Ssum,
                                               const float* __restrict__ A_log) {
  const int idx = blockIdx.x * 256 + threadIdx.x;  // over DINNER*16
  const int d = idx >> 4;
  const float a = -expf(A_log[idx]);
  float h = 0.f;
#pragma unroll 8
  for (int c = 0; c < NCHUNK; ++c) {
    float* p = H + (size_t)c * (DINNER * DSTATE) + idx;
    const float bl = *p;
    const float sv = Ssum[(size_t)c * DINNER + d];
    *p = h;
    h = h * __expf(a * sv) + bl;
  }
}

// K3: replay each chunk from entry state, y = h.C + D*x, fused silu(z) gate
__global__ __launch_bounds__(256) void k_scan3(const float* __restrict__ DT,
                                               const float* __restrict__ dt_b,
                                               const __bf16* __restrict__ XCS,
                                               const __bf16* __restrict__ XZ,
                                               const float* __restrict__ BC,
                                               const float* __restrict__ A_log,
                                               const float* __restrict__ Dp,
                                               const float* __restrict__ H,
                                               __bf16* __restrict__ Y) {
  const int d = blockIdx.x * 256 + threadIdx.x;
  const int c = blockIdx.y;
  const int t0 = c * CHL;
  __shared__ float s_bc[CHL][32];
  {
    int li = threadIdx.x;  // CHL*32 = 256
    s_bc[li >> 5][li & 31] = BC[(size_t)(t0 + (li >> 5)) * 32 + (li & 31)];
  }
  float a[16], h[16];
  const f32x4* alp = (const f32x4*)(A_log + (size_t)d * 16);
  const f32x4* hp = (const f32x4*)(H + ((size_t)c * DINNER + d) * 16);
#pragma unroll
  for (int q = 0; q < 4; ++q) {
    f32x4 v = alp[q];
    a[q * 4 + 0] = -expf(v.x); a[q * 4 + 1] = -expf(v.y);
    a[q * 4 + 2] = -expf(v.z); a[q * 4 + 3] = -expf(v.w);
    f32x4 hv = hp[q];
    h[q * 4 + 0] = hv.x; h[q * 4 + 1] = hv.y;
    h[q * 4 + 2] = hv.z; h[q * 4 + 3] = hv.w;
  }
  const float Dd = Dp[d];
  const float bias = dt_b[d];
  __syncthreads();
#pragma unroll
  for (int tt = 0; tt < CHL; ++tt) {
    const size_t idx = (size_t)(t0 + tt) * DINNER + d;
    const float dtv = softplusf_(DT[idx] + DT[idx + (size_t)SEQ * DINNER] + bias);
    const float xv = (float)XCS[idx];
    const float zv = (float)XZ[(size_t)(t0 + tt) * (2 * DINNER) + DINNER + d];
    const float u = dtv * xv;
    float y = 0.f;
#pragma unroll
    for (int n = 0; n < 16; ++n) {
      h[n] = h[n] * __expf(dtv * a[n]) + u * s_bc[tt][n];
      y += h[n] * s_bc[tt][16 + n];
    }
    Y[idx] = (__bf16)((y + Dd * xv) * siluf_(zv));
  }
}

extern "C" void kernel_launch(void* const* d_in, const int* in_sizes, int n_in,
                              void* d_out, int out_size, void* d_ws, size_t ws_size,
                              hipStream_t stream) {
  const int* tokens = (const int*)d_in[0];
  const float* embedding = (const float*)d_in[1];
  const float* norm_w = (const float*)d_in[2];
  const float* in_proj_w = (const float*)d_in[3];
  const float* conv_w = (const float*)d_in[4];
  const float* conv_b = (const float*)d_in[5];
  const float* x_proj_w = (const float*)d_in[6];
  const float* dt_w = (const float*)d_in[7];
  const float* dt_b = (const float*)d_in[8];
  const float* A_log = (const float*)d_in[9];
  const float* Dp = (const float*)d_in[10];
  const float* out_proj_w = (const float*)d_in[11];
  const float* normf_w = (const float*)d_in[12];
  const float* lm_head_w = (const float*)d_in[13];
  float* logits = (float*)d_out;

  char* ws = (char*)d_ws;
  float* X = (float*)(ws + 0);                   // 1024*768 f32
  __bf16* XN = (__bf16*)(ws + 3145728);          // 1024*768 bf16
  __bf16* XZ = (__bf16*)(ws + 4718592);          // 1024*3072 bf16
  __bf16* XCS = (__bf16*)(ws + 11010048);        // 1024*1536 bf16
  __bf16* XP = (__bf16*)(ws + 14155776);         // 1024*1568 bf16
  float* DT = (float*)(ws + 17367040);           // 2 x 1024*1536 f32 (split-K)
  float* BC = (float*)(ws + 29949952);           // 1024*32 f32
  __bf16* Y = (__bf16*)(ws + 30081024);          // 1024*1536 bf16
  float* Hloc = (float*)(ws + 33226752);         // 128*1536*16 f32 (12.6MB)
  float* Ssum = (float*)(ws + 45809664);         // 128*1536 f32
  __bf16* Wip = (__bf16*)(ws + 46596096);        // 4*3072*768  (18.87MB)
  __bf16* Wxp = (__bf16*)(ws + 65470464);        // 4*1568*1536 (19.27MB)
  __bf16* Wdt = (__bf16*)(ws + 84738048);        // 4*1536*1536 (18.87MB)
  __bf16* Wop = (__bf16*)(ws + 103612416);       // 4*768*1536  (9.44MB)
  const bool full = ws_size >= 113049600ull;     // proven >= 134479872 (r3)

  k_embed<<<768, 256, 0, stream>>>(tokens, embedding, X);
  if (full) {
    Cvt4Args ca;
    ca.s[0] = in_proj_w;  ca.d[0] = Wip;
    ca.s[1] = x_proj_w;   ca.d[1] = Wxp;
    ca.s[2] = dt_w;       ca.d[2] = Wdt;
    ca.s[3] = out_proj_w; ca.d[3] = Wop;
    ca.off[0] = 0;
    ca.off[1] = NLAYERS * 3072 * DIM;                   // 9437184
    ca.off[2] = ca.off[1] + NLAYERS * XPROJ_N * DINNER; // +9633792
    ca.off[3] = ca.off[2] + NLAYERS * DINNER * DINNER;  // +9437184
    ca.off[4] = ca.off[3] + NLAYERS * DIM * DINNER;     // = 33226752
    k_cvt4<<<(33226752 / 4 + 255) / 256, 256, 0, stream>>>(ca);
  }

  for (int l = 0; l < NLAYERS; ++l) {
    const float* Al = A_log + (size_t)l * DINNER * DSTATE;
    const float* bl = dt_b + (size_t)l * DINNER;

    k_rmsnorm<<<SEQ, 256, 0, stream>>>(X, norm_w + (size_t)l * DIM, XN);
    if (full) {
      k_gemm2<0><<<dim3(16, 48), 256, 0, stream>>>(
          XN, DIM, Wip + (size_t)l * 3072 * DIM, DIM, 2 * DINNER, DIM,
          nullptr, XZ, 2 * DINNER, 0);
    } else {
      k_gemm<0, 0, 64, 64><<<dim3(16, 48), 256, 0, stream>>>(
          XN, DIM, in_proj_w + (size_t)l * 3072 * DIM, DIM, 2 * DINNER,
          DIM, nullptr, XZ, 2 * DINNER, 0);
    }
    k_conv_silu<<<SEQ, 384, 0, stream>>>(
        XZ, conv_w + (size_t)l * DINNER * 4, conv_b + (size_t)l * DINNER, XCS);
    if (full) {
      k_gemm2<4><<<dim3(16, 25), 256, 0, stream>>>(
          XCS, DINNER, Wxp + (size_t)l * XPROJ_N * DINNER, DINNER,
          XPROJ_N, DINNER, BC, XP, XPROJ_N, 0);
      k_gemm2<3><<<dim3(16, 24, 2), 256, 0, stream>>>(
          XP, XPROJ_N, Wdt + (size_t)l * DINNER * DINNER, DINNER, DINNER,
          DINNER / 2, nullptr, DT, DINNER, SEQ * DINNER);
    } else {
      k_gemm<4, 0, 64, 64><<<dim3(16, 25), 256, 0, stream>>>(
          XCS, DINNER, x_proj_w + (size_t)l * XPROJ_N * DINNER, DINNER,
          XPROJ_N, DINNER, BC, XP, XPROJ_N, 0);
      k_gemm<3, 0, 64, 64><<<dim3(16, 24, 2), 256, 0, stream>>>(
          XP, XPROJ_N, dt_w + (size_t)l * DINNER * DINNER, DINNER,
          DINNER, DINNER / 2, nullptr, DT, DINNER, SEQ * DINNER);
    }
    k_scan1<<<dim3(6, NCHUNK), 256, 0, stream>>>(DT, bl, XCS, BC, Al, Hloc, Ssum);
    k_scan2<<<96, 256, 0, stream>>>(Hloc, Ssum, Al);
    k_scan3<<<dim3(6, NCHUNK), 256, 0, stream>>>(DT, bl, XCS, XZ, BC, Al,
                                                 Dp + (size_t)l * DINNER, Hloc, Y);
    if (full) {
      k_gemm2<2><<<dim3(16, 12, 2), 256, 0, stream>>>(
          Y, DINNER, Wop + (size_t)l * DIM * DINNER, DINNER, DIM,
          DINNER / 2, nullptr, X, DIM, 0);
    } else {
      k_gemm<2, 0, 64, 64><<<dim3(16, 12, 2), 256, 0, stream>>>(
          Y, DINNER, out_proj_w + (size_t)l * DIM * DINNER, DINNER,
          DIM, DINNER / 2, nullptr, X, DIM, 0);
    }
  }
  k_rmsnorm<<<SEQ, 256, 0, stream>>>(X, normf_w, XN);
  // lm_head: proven 128x128 dbuf fp32-W reg-staged + XCD swizzle (183us)
  k_gemm<3, 1, 128, 128><<<dim3(8, 393), 256, 0, stream>>>(
      XN, DIM, lm_head_w, DIM, VOCAB, DIM, nullptr, logits, VOCAB, 0);
}